// Round 18
// baseline (148.727 us; speedup 1.0000x reference)
//
#include <hip/hip_runtime.h>
#include <hip/hip_bf16.h>

#define V 17
#define C_DIM 256
#define TV 1088        // T*V
#define CTV 278528     // C*T*V

typedef __attribute__((ext_vector_type(8))) short short8;
typedef __attribute__((ext_vector_type(4))) short svec4;
typedef __attribute__((ext_vector_type(4))) float f32x4;

static __device__ inline short f2bfs(float f) {
    union { __hip_bfloat16 b; short s; } u;
    u.b = __float2bfloat16(f);
    return u.s;
}
static __device__ inline float bfs2f(short s) {
    union { float f; unsigned u; } q;
    q.u = ((unsigned)(unsigned short)s) << 16;
    return q.f;
}

// ws layout (bytes):
//   0      : wtb (65536 bf16)  blocked W^T: wtb[(kc*256+d)*32+kk] = W[kc*32+kk][d]
//   131072 : g   (4352 f32)    tanh(fm)+1
//   148480 : scl (4352 f32)    [u][d] = gamma[v,d]/sqrt(var[v,d]+eps),  v=(u+d)%17
//   165888 : ofs (4352 f32)    [u][d] = (lin_b[d]-mean[v,d])*scl+beta[v,d]
//   183296 : gnv (4352 f32)    [u][d] = 1/g[u][d]
__global__ __launch_bounds__(256) void prep_kernel(
    const float* __restrict__ fm, const float* __restrict__ W,
    const float* __restrict__ lb, const float* __restrict__ gamma,
    const float* __restrict__ beta, const float* __restrict__ mean,
    const float* __restrict__ var,
    __hip_bfloat16* __restrict__ wtb, float* __restrict__ g,
    float* __restrict__ scl, float* __restrict__ ofs, float* __restrict__ gnv)
{
    int i = blockIdx.x * 256 + threadIdx.x;   // 65536 threads
    int c = i >> 8, d = i & 255;
    float w = W[i];
    wtb[((c >> 5) * 256 + d) * 32 + (c & 31)] = __float2bfloat16(w);
    if (i < V * C_DIM) {
        float gv = tanhf(fm[i]) + 1.0f;
        g[i]   = gv;
        gnv[i] = 1.0f / gv;
        int u = i >> 8;                        // GEMM-row joint
        int v = u + d; v %= V;                 // OUTPUT joint = (u+d) mod 17
        int k = v * C_DIM + d;                 // BN parameter index
        float sc = gamma[k] * rsqrtf(var[k] + 1e-5f);
        scl[i] = sc;
        ofs[i] = (lb[d] - mean[k]) * sc + beta[k];
    }
}

// ---- staging task: gather 8 channels for row r, gate, cast, one short8 write
static __device__ __forceinline__ void stage_task(
    int t, short* As, const float* __restrict__ xplane, const float* __restrict__ g)
{
    int kkc = t / 68;                  // 16B slot index
    int r   = t - kkc * 68;            // 0..67
    int tl  = r / 17;
    int u   = r - tl * 17;
    int c0  = kkc * 8;
    const float* gp = g + u * C_DIM + c0;
    float4 g0 = *(const float4*)gp;
    float4 g1 = *(const float4*)(gp + 4);
    float gg[8] = {g0.x, g0.y, g0.z, g0.w, g1.x, g1.y, g1.z, g1.w};
    const float* xb = xplane + tl * V;
    int mm = (u + c0) % V;
    float xv[8];
    #pragma unroll
    for (int i = 0; i < 8; ++i) {
        xv[i] = xb[(c0 + i) * TV + mm];
        mm = (mm == V - 1) ? 0 : mm + 1;
    }
    short av[8];
    #pragma unroll
    for (int i = 0; i < 8; ++i) av[i] = f2bfs(xv[i] * gg[i]);
    *(short8*)(As + r * 256 + ((kkc ^ (r & 7)) << 3)) =
        (short8){av[0], av[1], av[2], av[3], av[4], av[5], av[6], av[7]};
}

// Block: 4 whole t-groups (68 GEMM rows, padded to 80), all 256 d.
// 512 thr / 8 waves. A-tile LDS: [80 rows][256 halves], XOR swizzle.
// KEY CHANGE vs r10: mi-OUTER passes. Each pass computes ONE 16-pos tile
// (acc = 2 f32x4 = 8 AGPR live, vs 40 for all 5 tiles) and runs its epilogue
// immediately. wtb fragments are re-read per pass (L2-resident, cheap).
// Peak regs ~70 -> __launch_bounds__(512,6): 6 waves/SIMD, 3 blocks/CU, 75%.
// MFMA swapped operands (verified r10..r17): arg0=wfr -> out row (lq*4+rg)=d,
// arg1=a -> out col (l15)=GEMM row. Epilogue: output joint vv=(pos%17+d)%17;
// residual x0[n,d,t,v] = As[pos][d] * (1/g[u][d]).
__global__ __launch_bounds__(512, 6) void shiftgcn_kernel(
    const float* __restrict__ x0, const __hip_bfloat16* __restrict__ wtb,
    const float* __restrict__ g, const float* __restrict__ scl,
    const float* __restrict__ ofs, const float* __restrict__ gnv,
    float* __restrict__ out)
{
    __shared__ __align__(16) short As[80 * 256];   // 40960 B

    const int tid  = threadIdx.x;
    const int lane = tid & 63;
    const int wv   = tid >> 6;                // 0..7
    const int l15  = lane & 15;
    const int lq   = lane >> 4;

    // T1: 1024 wg = 8 XCD x 128 contiguous tiles (bijective)
    const int wg  = (blockIdx.x & 7) * 128 + (blockIdx.x >> 3);
    const int nt0 = wg * 4;
    const int n   = nt0 >> 6;
    const int tb  = nt0 & 63;                 // multiple of 4
    const float* xplane = x0 + n * CTV + tb * V;   // + c*TV + tl*V + joint

    // zero pad rows 68..79 (12 rows * 256 halves = 384 short8)
    if (tid < 384) ((short8*)(As + 68 * 256))[tid] = (short8)0;

    // ---- Phase 1: stage all K. 2176 tasks = 4 full rounds + 128-thread tail.
    #pragma unroll 1
    for (int it = 0; it < 4; ++it)
        stage_task(it * 512 + tid, As, xplane, g);
    if (tid < 128)
        stage_task(2048 + tid, As, xplane, g);
    __syncthreads();   // the ONLY barrier

    // ---- Phase 2+3 interleaved: 5 mi-passes, each {K-loop with 8-AGPR acc,
    //      then that tile's epilogue}.
    #pragma unroll 1
    for (int mi = 0; mi < 5; ++mi) {
        const int pos  = mi * 16 + l15;       // GEMM row this lane owns
        const int arow = pos * 256;
        const int psw  = (pos & 7);

        f32x4 acc0 = (f32x4){0.f, 0.f, 0.f, 0.f};
        f32x4 acc1 = (f32x4){0.f, 0.f, 0.f, 0.f};

        #pragma unroll
        for (int kc = 0; kc < 8; ++kc) {
            short8 w0 = *(const short8*)(wtb +
                ((kc * 256 + wv * 32 + l15) << 5) + lq * 8);
            short8 w1 = *(const short8*)(wtb +
                ((kc * 256 + wv * 32 + 16 + l15) << 5) + lq * 8);
            short8 a = *(const short8*)(As + arow +
                ((((kc << 2) | lq) ^ psw) << 3));
            acc0 = __builtin_amdgcn_mfma_f32_16x16x32_bf16(w0, a, acc0, 0, 0, 0);
            acc1 = __builtin_amdgcn_mfma_f32_16x16x32_bf16(w1, a, acc1, 0, 0, 0);
        }

        if (pos < 68) {
            const int tl = pos / 17;
            const int ur = pos - tl * 17;
            #pragma unroll
            for (int ni = 0; ni < 2; ++ni) {
                const f32x4 A = ni ? acc1 : acc0;
                const int D0 = wv * 32 + ni * 16 + lq * 4;
                const int dm = D0 % V;
                float4 s4 = *(const float4*)(scl + ur * C_DIM + D0);
                float4 o4 = *(const float4*)(ofs + ur * C_DIM + D0);
                float4 g4 = *(const float4*)(gnv + ur * C_DIM + D0);
                float ss[4] = {s4.x, s4.y, s4.z, s4.w};
                float oo[4] = {o4.x, o4.y, o4.z, o4.w};
                float gi[4] = {g4.x, g4.y, g4.z, g4.w};
                // residual: 4 consecutive bf16 at As[pos][D0..D0+3]
                int hb = arow + ((((D0 >> 3) ^ psw) << 3) | (D0 & 7));
                svec4 a4 = *(const svec4*)(As + hb);
                int vv = ur + dm; if (vv >= V) vv -= V;   // output joint, rg=0
                int base2 = n * CTV + D0 * TV + (tb + tl) * V;
                #pragma unroll
                for (int rg = 0; rg < 4; ++rg) {
                    float x = bfs2f(a4[rg]) * gi[rg];
                    float val = A[rg] * ss[rg] + oo[rg] + x;
                    out[base2 + rg * TV + vv] = fmaxf(val, 0.f);
                    if (++vv == V) vv = 0;
                }
            }
        }
    }
}

extern "C" void kernel_launch(void* const* d_in, const int* in_sizes, int n_in,
                              void* d_out, int out_size, void* d_ws, size_t ws_size,
                              hipStream_t stream)
{
    const float* x0    = (const float*)d_in[0];
    const float* fm    = (const float*)d_in[1];
    const float* W     = (const float*)d_in[2];
    const float* lb    = (const float*)d_in[3];
    const float* gamma = (const float*)d_in[4];
    const float* beta  = (const float*)d_in[5];
    const float* mean  = (const float*)d_in[6];
    const float* var   = (const float*)d_in[7];
    float* out = (float*)d_out;

    char* ws = (char*)d_ws;
    __hip_bfloat16* wtb = (__hip_bfloat16*)ws;
    float* g   = (float*)(ws + 131072);
    float* scl = (float*)(ws + 148480);
    float* ofs = (float*)(ws + 165888);
    float* gnv = (float*)(ws + 183296);

    prep_kernel<<<256, 256, 0, stream>>>(fm, W, lb, gamma, beta, mean, var,
                                         wtb, g, scl, ofs, gnv);
    shiftgcn_kernel<<<1024, 512, 0, stream>>>(x0, wtb, g, scl, ofs, gnv, out);
}

// Round 19
// 50.064 us; speedup vs baseline: 2.9708x; 2.9708x over previous
//
#include <hip/hip_runtime.h>
#include <hip/hip_bf16.h>

#define V 17
#define C_DIM 256
#define TV 1088        // T*V
#define CTV 278528     // C*T*V

typedef __attribute__((ext_vector_type(8))) short short8;
typedef __attribute__((ext_vector_type(4))) short svec4;
typedef __attribute__((ext_vector_type(4))) float f32x4;

static __device__ inline short f2bfs(float f) {
    union { __hip_bfloat16 b; short s; } u;
    u.b = __float2bfloat16(f);
    return u.s;
}
static __device__ inline float bfs2f(short s) {
    union { float f; unsigned u; } q;
    q.u = ((unsigned)(unsigned short)s) << 16;
    return q.f;
}

// ws layout (bytes):
//   0      : wtb  (65536 bf16)   blocked W^T: wtb[(kc*256+d)*32+kk] = W[kc*32+kk][d]
//   131072 : g    (4352 f32)     tanh(fm)+1
//   148480 : tbl2 (4352 float2)  [d][17] {scl, ofs}: scl=gamma[v,d]*rsqrt(var+eps),
//                                ofs=(lb[d]-mean[v,d])*scl+beta[v,d], v=(u+d)%17
//   183296 : gnvt (4352 f32)     [d][17] 1/g[u][d]
//   (148480..200704 is one contiguous 52224B blob staged to LDS by the main kernel)
__global__ __launch_bounds__(256) void prep_kernel(
    const float* __restrict__ fm, const float* __restrict__ W,
    const float* __restrict__ lb, const float* __restrict__ gamma,
    const float* __restrict__ beta, const float* __restrict__ mean,
    const float* __restrict__ var,
    __hip_bfloat16* __restrict__ wtb, float* __restrict__ g,
    float2* __restrict__ tbl2, float* __restrict__ gnvt)
{
    int i = blockIdx.x * 256 + threadIdx.x;   // 65536 threads
    int c = i >> 8, d = i & 255;
    float w = W[i];
    wtb[((c >> 5) * 256 + d) * 32 + (c & 31)] = __float2bfloat16(w);
    if (i < V * C_DIM) {
        int u = i >> 8;                        // GEMM-row joint
        float gv = tanhf(fm[i]) + 1.0f;
        g[i] = gv;
        gnvt[d * V + u] = 1.0f / gv;
        int v = u + d; v %= V;                 // OUTPUT joint = (u+d) mod 17
        int k = v * C_DIM + d;                 // BN parameter index
        float sc = gamma[k] * rsqrtf(var[k] + 1e-5f);
        tbl2[d * V + u] = make_float2(sc, (lb[d] - mean[k]) * sc + beta[k]);
    }
}

// ---- staging task: gather 8 channels for row r, gate, cast, one short8 write
static __device__ __forceinline__ void stage_task(
    int t, short* As, const float* __restrict__ xplane, const float* __restrict__ g)
{
    int kkc = t / 68;                  // 16B slot index
    int r   = t - kkc * 68;            // 0..67
    int tl  = r / 17;
    int u   = r - tl * 17;
    int c0  = kkc * 8;
    const float* gp = g + u * C_DIM + c0;
    float4 g0 = *(const float4*)gp;
    float4 g1 = *(const float4*)(gp + 4);
    float gg[8] = {g0.x, g0.y, g0.z, g0.w, g1.x, g1.y, g1.z, g1.w};
    const float* xb = xplane + tl * V;
    int mm = (u + c0) % V;
    float xv[8];
    #pragma unroll
    for (int i = 0; i < 8; ++i) {
        xv[i] = xb[(c0 + i) * TV + mm];
        mm = (mm == V - 1) ? 0 : mm + 1;
    }
    short av[8];
    #pragma unroll
    for (int i = 0; i < 8; ++i) av[i] = f2bfs(xv[i] * gg[i]);
    *(short8*)(As + r * 256 + ((kkc ^ (r & 7)) << 3)) =
        (short8){av[0], av[1], av[2], av[3], av[4], av[5], av[6], av[7]};
}

// Block: 4 whole t-groups (68 GEMM rows, padded to 80), all 256 d.
// 512 thr / 8 waves. A-tile LDS: [80 rows][256 halves], XOR swizzle.
// r10 structure + TA-offload epilogue:
//   stage As | barrier | K-loop (MFMA, swapped operands) | pre-read residuals
//   from As into regs | barrier | overwrite LDS with transposed BN tables
//   ([d][17] -> conflict-free ds_read, replacing 64-line/instr L1 gathers)
//   | barrier | epilogue (output shift v=(pos%17+d)%17, scatter stores).
__global__ __launch_bounds__(512, 4) void shiftgcn_kernel(
    const float* __restrict__ x0, const __hip_bfloat16* __restrict__ wtb,
    const float* __restrict__ g, const float4* __restrict__ tblsrc,
    float* __restrict__ out)
{
    __shared__ __align__(16) char smem[52224];
    short*  As = (short*)smem;                 // phase A: [80][256] swizzled
    float2* T2 = (float2*)smem;                // phase B: [256][17] {scl,ofs}
    float*  Tg = (float*)(smem + 34816);       // phase B: [256][17] gnv

    const int tid  = threadIdx.x;
    const int lane = tid & 63;
    const int wv   = tid >> 6;                // 0..7
    const int l15  = lane & 15;
    const int lq   = lane >> 4;

    // T1: 1024 wg = 8 XCD x 128 contiguous tiles (bijective)
    const int wg  = (blockIdx.x & 7) * 128 + (blockIdx.x >> 3);
    const int nt0 = wg * 4;
    const int n   = nt0 >> 6;
    const int tb  = nt0 & 63;                 // multiple of 4
    const float* xplane = x0 + n * CTV + tb * V;   // + c*TV + tl*V + joint

    // zero pad rows 68..79 (12 rows * 256 halves = 384 short8)
    if (tid < 384) ((short8*)(As + 68 * 256))[tid] = (short8)0;

    // ---- Phase 1: stage all K. 2176 tasks = 4 full rounds + 128-thread tail.
    #pragma unroll 1
    for (int it = 0; it < 4; ++it)
        stage_task(it * 512 + tid, As, xplane, g);
    if (tid < 128)
        stage_task(2048 + tid, As, xplane, g);
    __syncthreads();

    // ---- Phase 2: MFMA, swapped operands. Wave wv owns d in [wv*32,wv*32+32).
    f32x4 acc[2][5];   // [dTile][posTile]
    #pragma unroll
    for (int ni = 0; ni < 2; ++ni)
        #pragma unroll
        for (int mi = 0; mi < 5; ++mi)
            acc[ni][mi] = (f32x4){0.f, 0.f, 0.f, 0.f};

    #pragma unroll
    for (int kc = 0; kc < 8; ++kc) {
        short8 wfr[2];
        #pragma unroll
        for (int ni = 0; ni < 2; ++ni)
            wfr[ni] = *(const short8*)(wtb +
                ((kc * 256 + wv * 32 + ni * 16 + l15) << 5) + lq * 8);
        #pragma unroll
        for (int mi = 0; mi < 5; ++mi) {
            int row = mi * 16 + l15;
            short8 a = *(const short8*)(As + row * 256 +
                ((((kc << 2) | lq) ^ (row & 7)) << 3));
            acc[0][mi] = __builtin_amdgcn_mfma_f32_16x16x32_bf16(wfr[0], a, acc[0][mi], 0, 0, 0);
            acc[1][mi] = __builtin_amdgcn_mfma_f32_16x16x32_bf16(wfr[1], a, acc[1][mi], 0, 0, 0);
        }
    }

    // ---- pre-read residual bf16 quads from As (rows >=68 are zero: harmless)
    svec4 res[2][5];
    #pragma unroll
    for (int ni = 0; ni < 2; ++ni) {
        const int D0 = wv * 32 + ni * 16 + lq * 4;
        #pragma unroll
        for (int mi = 0; mi < 5; ++mi) {
            const int pos = mi * 16 + l15;
            res[ni][mi] = *(const svec4*)(As + pos * 256 +
                ((((D0 >> 3) ^ (pos & 7)) << 3) | (D0 & 7)));
        }
    }
    __syncthreads();   // As dead

    // ---- stage transposed tables into LDS (contiguous 52224B blob)
    #pragma unroll
    for (int j = tid; j < 3264; j += 512)
        ((float4*)smem)[j] = tblsrc[j];
    __syncthreads();

    // ---- Phase 3: epilogue. pos = mi*16+l15 (joint ur), d = wv*32+ni*16+lq*4+rg,
    //      output joint vv = (ur+d)%17. Tables via conflict-free LDS reads.
    #pragma unroll
    for (int ni = 0; ni < 2; ++ni) {
        const int D0 = wv * 32 + ni * 16 + lq * 4;
        const int dm = D0 % V;
        #pragma unroll
        for (int mi = 0; mi < 5; ++mi) {
            const int pos = mi * 16 + l15;
            if (pos < 68) {
                const int tl = pos / 17;
                const int ur = pos - tl * 17;
                int vv = ur + dm; if (vv >= V) vv -= V;   // output joint, rg=0
                const int base2 = n * CTV + D0 * TV + (tb + tl) * V;
                #pragma unroll
                for (int rg = 0; rg < 4; ++rg) {
                    float2 so = T2[(D0 + rg) * V + ur];
                    float  gi = Tg[(D0 + rg) * V + ur];
                    float x = bfs2f(res[ni][mi][rg]) * gi;
                    float val = acc[ni][mi][rg] * so.x + so.y + x;
                    out[base2 + rg * TV + vv] = fmaxf(val, 0.f);
                    if (++vv == V) vv = 0;
                }
            }
        }
    }
}

extern "C" void kernel_launch(void* const* d_in, const int* in_sizes, int n_in,
                              void* d_out, int out_size, void* d_ws, size_t ws_size,
                              hipStream_t stream)
{
    const float* x0    = (const float*)d_in[0];
    const float* fm    = (const float*)d_in[1];
    const float* W     = (const float*)d_in[2];
    const float* lb    = (const float*)d_in[3];
    const float* gamma = (const float*)d_in[4];
    const float* beta  = (const float*)d_in[5];
    const float* mean  = (const float*)d_in[6];
    const float* var   = (const float*)d_in[7];
    float* out = (float*)d_out;

    char* ws = (char*)d_ws;
    __hip_bfloat16* wtb = (__hip_bfloat16*)ws;
    float*  g    = (float*)(ws + 131072);
    float2* tbl2 = (float2*)(ws + 148480);
    float*  gnvt = (float*)(ws + 183296);

    prep_kernel<<<256, 256, 0, stream>>>(fm, W, lb, gamma, beta, mean, var,
                                         wtb, g, tbl2, gnvt);
    shiftgcn_kernel<<<1024, 512, 0, stream>>>(x0, wtb, g,
                                              (const float4*)(ws + 148480), out);
}

// Round 20
// 49.769 us; speedup vs baseline: 2.9884x; 1.0059x over previous
//
#include <hip/hip_runtime.h>
#include <hip/hip_bf16.h>

#define V 17
#define C_DIM 256
#define TV 1088        // T*V
#define CTV 278528     // C*T*V

typedef __attribute__((ext_vector_type(8))) short short8;
typedef __attribute__((ext_vector_type(4))) short svec4;
typedef __attribute__((ext_vector_type(4))) float f32x4;

static __device__ inline short f2bfs(float f) {
    union { __hip_bfloat16 b; short s; } u;
    u.b = __float2bfloat16(f);
    return u.s;
}
static __device__ inline float bfs2f(short s) {
    union { float f; unsigned u; } q;
    q.u = ((unsigned)(unsigned short)s) << 16;
    return q.f;
}

// ws layout (bytes):
//   0      : wtb   (65536 bf16)  blocked W^T: wtb[(kc*256+d)*32+kk] = W[kc*32+kk][d]
//   131072 : g     (4352 f32)    tanh(fm)+1
//   148480 : scl_t (4352 f32)    [u][d'] swizzled: gamma[v,d]*rsqrt(var+eps), v=(u+d)%17
//   165888 : ofs_t (4352 f32)    [u][d'] swizzled: (lb[d]-mean[v,d])*scl+beta[v,d]
//   183296 : gnv_t (4352 f32)    [u][d'] swizzled: 1/g[u][d]
//   d' = (((d>>2) ^ (u&7)) << 2) | (d&3)  -- float4-slot XOR swizzle so that
//   LDS reads at fixed d, lanes varying u, spread across 8 slots (2-way, free).
//   148480..200704 is one contiguous 52224B blob staged verbatim to LDS.
__global__ __launch_bounds__(256) void prep_kernel(
    const float* __restrict__ fm, const float* __restrict__ W,
    const float* __restrict__ lb, const float* __restrict__ gamma,
    const float* __restrict__ beta, const float* __restrict__ mean,
    const float* __restrict__ var,
    __hip_bfloat16* __restrict__ wtb, float* __restrict__ g,
    float* __restrict__ scl_t, float* __restrict__ ofs_t,
    float* __restrict__ gnv_t)
{
    int i = blockIdx.x * 256 + threadIdx.x;   // 65536 threads
    int c = i >> 8, d = i & 255;
    float w = W[i];
    wtb[((c >> 5) * 256 + d) * 32 + (c & 31)] = __float2bfloat16(w);
    if (i < V * C_DIM) {
        int u = i >> 8;                        // GEMM-row joint
        float gv = tanhf(fm[i]) + 1.0f;
        g[i] = gv;
        int dsw = ((((d >> 2) ^ (u & 7)) << 2) | (d & 3));
        gnv_t[u * C_DIM + dsw] = 1.0f / gv;
        int v = u + d; v %= V;                 // OUTPUT joint = (u+d) mod 17
        int k = v * C_DIM + d;                 // BN parameter index
        float sc = gamma[k] * rsqrtf(var[k] + 1e-5f);
        scl_t[u * C_DIM + dsw] = sc;
        ofs_t[u * C_DIM + dsw] = (lb[d] - mean[k]) * sc + beta[k];
    }
}

// ---- staging task: gather 8 channels for row r, gate, cast, one short8 write
static __device__ __forceinline__ void stage_task(
    int t, short* As, const float* __restrict__ xplane, const float* __restrict__ g)
{
    int kkc = t / 68;                  // 16B slot index
    int r   = t - kkc * 68;            // 0..67
    int tl  = r / 17;
    int u   = r - tl * 17;
    int c0  = kkc * 8;
    const float* gp = g + u * C_DIM + c0;
    float4 g0 = *(const float4*)gp;
    float4 g1 = *(const float4*)(gp + 4);
    float gg[8] = {g0.x, g0.y, g0.z, g0.w, g1.x, g1.y, g1.z, g1.w};
    const float* xb = xplane + tl * V;
    int mm = (u + c0) % V;
    float xv[8];
    #pragma unroll
    for (int i = 0; i < 8; ++i) {
        xv[i] = xb[(c0 + i) * TV + mm];
        mm = (mm == V - 1) ? 0 : mm + 1;
    }
    short av[8];
    #pragma unroll
    for (int i = 0; i < 8; ++i) av[i] = f2bfs(xv[i] * gg[i]);
    *(short8*)(As + r * 256 + ((kkc ^ (r & 7)) << 3)) =
        (short8){av[0], av[1], av[2], av[3], av[4], av[5], av[6], av[7]};
}

// Block: 4 whole t-groups (68 GEMM rows, padded to 80), all 256 d.
// 512 thr / 8 waves. A-tile LDS: [80 rows][256 halves], XOR swizzle.
// r19 structure (TA-offloaded tables) + swizzled-[u][d] table format:
// each epilogue step reads one ds_read_b128 PER TABLE (3 total) instead of
// 8 scalarized reads -- LDS-instr count 80->30/thread, ~2-way conflicts.
__global__ __launch_bounds__(512, 4) void shiftgcn_kernel(
    const float* __restrict__ x0, const __hip_bfloat16* __restrict__ wtb,
    const float* __restrict__ g, const float4* __restrict__ tblsrc,
    float* __restrict__ out)
{
    __shared__ __align__(16) char smem[52224];
    short* As = (short*)smem;                  // phase A: [80][256] swizzled
    float* Ts = (float*)smem;                  // phase B: scl [17][256] swz
    float* To = (float*)(smem + 17408);        // phase B: ofs [17][256] swz
    float* Tg = (float*)(smem + 34816);        // phase B: gnv [17][256] swz

    const int tid  = threadIdx.x;
    const int lane = tid & 63;
    const int wv   = tid >> 6;                // 0..7
    const int l15  = lane & 15;
    const int lq   = lane >> 4;

    // T1: 1024 wg = 8 XCD x 128 contiguous tiles (bijective)
    const int wg  = (blockIdx.x & 7) * 128 + (blockIdx.x >> 3);
    const int nt0 = wg * 4;
    const int n   = nt0 >> 6;
    const int tb  = nt0 & 63;                 // multiple of 4
    const float* xplane = x0 + n * CTV + tb * V;   // + c*TV + tl*V + joint

    // zero pad rows 68..79 (12 rows * 256 halves = 384 short8)
    if (tid < 384) ((short8*)(As + 68 * 256))[tid] = (short8)0;

    // ---- Phase 1: stage all K. 2176 tasks = 4 full rounds + 128-thread tail.
    #pragma unroll 1
    for (int it = 0; it < 4; ++it)
        stage_task(it * 512 + tid, As, xplane, g);
    if (tid < 128)
        stage_task(2048 + tid, As, xplane, g);
    __syncthreads();

    // ---- Phase 2: MFMA, swapped operands. Wave wv owns d in [wv*32,wv*32+32).
    f32x4 acc[2][5];   // [dTile][posTile]
    #pragma unroll
    for (int ni = 0; ni < 2; ++ni)
        #pragma unroll
        for (int mi = 0; mi < 5; ++mi)
            acc[ni][mi] = (f32x4){0.f, 0.f, 0.f, 0.f};

    #pragma unroll
    for (int kc = 0; kc < 8; ++kc) {
        short8 wfr[2];
        #pragma unroll
        for (int ni = 0; ni < 2; ++ni)
            wfr[ni] = *(const short8*)(wtb +
                ((kc * 256 + wv * 32 + ni * 16 + l15) << 5) + lq * 8);
        #pragma unroll
        for (int mi = 0; mi < 5; ++mi) {
            int row = mi * 16 + l15;
            short8 a = *(const short8*)(As + row * 256 +
                ((((kc << 2) | lq) ^ (row & 7)) << 3));
            acc[0][mi] = __builtin_amdgcn_mfma_f32_16x16x32_bf16(wfr[0], a, acc[0][mi], 0, 0, 0);
            acc[1][mi] = __builtin_amdgcn_mfma_f32_16x16x32_bf16(wfr[1], a, acc[1][mi], 0, 0, 0);
        }
    }

    // ---- pre-read residual bf16 quads from As (rows >=68 are zero: harmless)
    svec4 res[2][5];
    #pragma unroll
    for (int ni = 0; ni < 2; ++ni) {
        const int D0 = wv * 32 + ni * 16 + lq * 4;
        #pragma unroll
        for (int mi = 0; mi < 5; ++mi) {
            const int pos = mi * 16 + l15;
            res[ni][mi] = *(const svec4*)(As + pos * 256 +
                ((((D0 >> 3) ^ (pos & 7)) << 3) | (D0 & 7)));
        }
    }
    __syncthreads();   // As dead

    // ---- stage swizzled tables into LDS (contiguous 52224B blob, verbatim)
    #pragma unroll
    for (int j = tid; j < 3264; j += 512)
        ((float4*)smem)[j] = tblsrc[j];
    __syncthreads();

    // ---- Phase 3: epilogue. pos = mi*16+l15 (joint ur), d = wv*32+ni*16+lq*4+rg,
    //      output joint vv = (ur+d)%17. One b128 LDS read per table per step.
    #pragma unroll
    for (int ni = 0; ni < 2; ++ni) {
        const int D0 = wv * 32 + ni * 16 + lq * 4;
        const int dm = D0 % V;
        const int s0 = D0 >> 2;                // float4 slot of D0 (d&3 == 0)
        #pragma unroll
        for (int mi = 0; mi < 5; ++mi) {
            const int pos = mi * 16 + l15;
            if (pos < 68) {
                const int tl = pos / 17;
                const int ur = pos - tl * 17;
                const int to = ur * C_DIM + ((s0 ^ (ur & 7)) << 2);
                float4 s4 = *(const float4*)(Ts + to);
                float4 o4 = *(const float4*)(To + to);
                float4 g4 = *(const float4*)(Tg + to);
                float ss[4] = {s4.x, s4.y, s4.z, s4.w};
                float oo[4] = {o4.x, o4.y, o4.z, o4.w};
                float gi[4] = {g4.x, g4.y, g4.z, g4.w};
                int vv = ur + dm; if (vv >= V) vv -= V;   // output joint, rg=0
                const int base2 = n * CTV + D0 * TV + (tb + tl) * V;
                #pragma unroll
                for (int rg = 0; rg < 4; ++rg) {
                    float x = bfs2f(res[ni][mi][rg]) * gi[rg];
                    float val = acc[ni][mi][rg] * ss[rg] + oo[rg] + x;
                    out[base2 + rg * TV + vv] = fmaxf(val, 0.f);
                    if (++vv == V) vv = 0;
                }
            }
        }
    }
}

extern "C" void kernel_launch(void* const* d_in, const int* in_sizes, int n_in,
                              void* d_out, int out_size, void* d_ws, size_t ws_size,
                              hipStream_t stream)
{
    const float* x0    = (const float*)d_in[0];
    const float* fm    = (const float*)d_in[1];
    const float* W     = (const float*)d_in[2];
    const float* lb    = (const float*)d_in[3];
    const float* gamma = (const float*)d_in[4];
    const float* beta  = (const float*)d_in[5];
    const float* mean  = (const float*)d_in[6];
    const float* var   = (const float*)d_in[7];
    float* out = (float*)d_out;

    char* ws = (char*)d_ws;
    __hip_bfloat16* wtb = (__hip_bfloat16*)ws;
    float* g     = (float*)(ws + 131072);
    float* scl_t = (float*)(ws + 148480);
    float* ofs_t = (float*)(ws + 165888);
    float* gnv_t = (float*)(ws + 183296);

    prep_kernel<<<256, 256, 0, stream>>>(fm, W, lb, gamma, beta, mean, var,
                                         wtb, g, scl_t, ofs_t, gnv_t);
    shiftgcn_kernel<<<1024, 512, 0, stream>>>(x0, wtb, g,
                                              (const float4*)(ws + 148480), out);
}